// Round 5
// baseline (371.502 us; speedup 1.0000x reference)
//
#include <hip/hip_runtime.h>

typedef __attribute__((ext_vector_type(8))) short short8;
typedef __attribute__((ext_vector_type(4))) float f32x4;
typedef __attribute__((ext_vector_type(4))) unsigned int u32x4;
typedef __attribute__((ext_vector_type(2))) unsigned int u32x2;
typedef __attribute__((ext_vector_type(4))) unsigned short u16x4;

#define NHEADS 16
#define DHEAD 64
#define SEQ 2048
#define BATCH 4
#define HD 1024
#define MTOT 8192  // BATCH*SEQ

// RNE f32->bf16 (cold paths)
static __device__ __forceinline__ unsigned short f2b(float x) {
  unsigned u = __builtin_bit_cast(unsigned, x);
  u += 0x7fffu + ((u >> 16) & 1u);
  return (unsigned short)(u >> 16);
}

// round-half-up pack of two f32 -> bf16x2 (<=0.5 ulp, 4 insts; hot paths)
static __device__ __forceinline__ unsigned pk2h(float lo, float hi) {
  unsigned a = __builtin_bit_cast(unsigned, lo) + 0x8000u;
  unsigned b = __builtin_bit_cast(unsigned, hi) + 0x8000u;
  return (a >> 16) | (b & 0xffff0000u);
}

// async global -> LDS, 16B per lane. LDS dst = wave-uniform base + lane*16.
static __device__ __forceinline__ void gll16(const void* g, void* l) {
  __builtin_amdgcn_global_load_lds(
      (const __attribute__((address_space(1))) unsigned int*)g,
      (__attribute__((address_space(3))) unsigned int*)l, 16, 0, 0);
}

// ---------------- f32 -> bf16 conversion (hidden states) ----------------
__global__ void cvt_bf16(const float* __restrict__ src,
                         unsigned short* __restrict__ dst, int n4) {
  int i = blockIdx.x * blockDim.x + threadIdx.x;
  if (i < n4) {
    f32x4 v = ((const f32x4*)src)[i];
    u16x4 o;
    o[0] = f2b(v[0]); o[1] = f2b(v[1]); o[2] = f2b(v[2]); o[3] = f2b(v[3]);
    ((u16x4*)dst)[i] = o;
  }
}

// ---- combined prep: Wq/Wk/Wv -> bf16, wmask = bf16(exp(mask)) ----
#define WQ4 (HD * HD / 4)   // 262144 vec4s per weight matrix
__global__ void prep(const float* __restrict__ Wq, const float* __restrict__ Wk,
                     const float* __restrict__ Wv, const float* __restrict__ mask,
                     unsigned short* __restrict__ Wb,
                     unsigned short* __restrict__ Wm) {
  int i = blockIdx.x * blockDim.x + threadIdx.x;
  if (i < 3 * WQ4) {
    int rg = i / WQ4;
    int idx = i - rg * WQ4;
    const float* src = (rg == 0) ? Wq : (rg == 1) ? Wk : Wv;
    f32x4 v = ((const f32x4*)src)[idx];
    u16x4 o;
    o[0] = f2b(v[0]); o[1] = f2b(v[1]); o[2] = f2b(v[2]); o[3] = f2b(v[3]);
    ((u16x4*)(Wb + (size_t)rg * HD * HD))[idx] = o;
  } else {
    int j = i - 3 * WQ4;            // 0..2047 vec4s of mask
    f32x4 v = ((const f32x4*)mask)[j];
    u16x4 o;
    o[0] = f2b(__expf(v[0])); o[1] = f2b(__expf(v[1]));
    o[2] = f2b(__expf(v[2])); o[3] = f2b(__expf(v[3]));
    ((u16x4*)Wm)[j] = o;
  }
}

// ---------------- fused QKV GEMM: 256x256, 16 waves, 8-phase -------------
// R12: same 8-phase counted-vmcnt schedule as R9 (race-free 3 rounds) but
// reshaped so per-wave state fits a 128-VGPR budget BY CONSTRUCTION:
// 1024 thr = 16 waves (4M x 4N), per-wave output 64x64 -> acc[4][4] = 64
// VGPR; per-phase frags af[2]+bf[4] = 24; total ~115 < 128. (R9-R11: 8
// waves x 128x64 -> acc alone = 128; allocator pinned at 128 VGPRs by its
// 4-wave/EU occupancy target and spilled acc -> WRITE_SIZE 115MB, MfmaUtil
// 13%. launch_bounds(512,2) and amdgpu_waves_per_eu(2,2) both failed to
// lift the budget.) Side benefit: 4 waves/SIMD (was 2) = 2x TLP.
//
// Phases per K-tile: (ks, mh) = (K-half 0/1, M-row-half 0/1); every wave
// reads all its 64 A-rows' mh-half + all 64 B-rows at k-half ks each phase.
// Stripes (16KB = 1 gll16/thread each):
//   A: rows with bit5==mh, layout [256][8 chunk-slots], XOR swizzle
//      (slot s at row r holds global chunk s^(r&7)) -- unchanged from R9.
//   B: k-half kh, NEW layout [kh][256 rows][4 slots x 16B], linear (slot s
//      = chunk s). bf reads are a contiguous 1KB/wave -> conflict-free.
// Per phase: {6 ds_read_b128 | 1 stage unit -> s_barrier -> lgkmcnt(0) ->
// setprio(1) -> 8 MFMA -> setprio(0) -> s_barrier}. vmcnt(2) only at
// phases 4/8 (2 stripes in flight; never drain to 0).
//
// Steady state (iter computes t0 on buf0 ph1-4, t1 on buf1 ph5-8), stage
// slot legality = "phase after the stripe's last read":
//   ph1 (0,ks0,mh0): SA(1,mh1,t1)  [buf1.A-mh1 last read prev ph8]
//   ph2 (0,ks0,mh1): SB(1,ks1,t1)  [buf1.B-ks1 last read prev ph8]
//   ph3 (0,ks1,mh0): SB(0,ks0,t0+2)[buf0.B-ks0 read ph1,2]
//   ph4 (0,ks1,mh1): SA(0,mh0,t0+2)[buf0.A-mh0 read ph1,3]; vmcnt(2)
//        -> all but ph3,4 landed -> buf1(t1) complete. barrier.
//   ph5 (1,ks0,mh0): SA(0,mh1,t0+2)[read ph2,4]
//   ph6 (1,ks0,mh1): SB(0,ks1,t0+2)[read ph3,4]
//   ph7 (1,ks1,mh0): SB(1,ks0,t1+2)[read ph5,6]
//   ph8 (1,ks1,mh1): SA(1,mh0,t1+2)[read ph5,7]; vmcnt(2) -> buf0(t0+2)
//        complete. barrier.
// Prologue: 4 stripes of tile0 + B-ks0,A-mh0 of tile1 (last 2 issued),
// vmcnt(2), barrier. Tail stages wrap k by &1023 (junk, never computed).
//
// R8 kept: m-slab XCD swizzle (FETCH 211->61MB), gather-side XOR swizzle.
__global__ __launch_bounds__(1024) void qkv_gemm(
    const unsigned short* __restrict__ X,
    const unsigned short* __restrict__ Wall,
    const float* __restrict__ bq, const float* __restrict__ bk,
    const float* __restrict__ bv,
    const float* __restrict__ rel,          // [2048][64] f32
    const float* __restrict__ mask,         // [4][2048] f32
    unsigned short* __restrict__ Qo,
    unsigned short* __restrict__ Ko,
    unsigned short* __restrict__ Vt) {
  __shared__ __align__(16) unsigned short As[2][256 * 64];   // [buf][row*64]
  __shared__ __align__(16) unsigned short Bs[2][2 * 256 * 32]; // [buf][kh*8192+row*32]

  const int t = threadIdx.x;           // 0..1023
  const int lane = t & 63;
  const int w = t >> 6;                // 0..15
  const int wm = w >> 2;               // 0..3 (M strip, 64 rows)
  const int wn = w & 3;                // 0..3 (N strip, 64 cols)

  // XCD swizzle: 4 m-tiles pinned per XCD (2MB X slab, L2-resident);
  // consecutive li share a panel so each W panel is fetched ~once per XCD.
  const int n = blockIdx.x;            // 0..383
  const int xcd = n & 7;
  const int li = n >> 3;               // 0..47
  const int bx = xcd * 4 + (li & 3);   // m-tile 0..31
  const int pp = li >> 2;              // 0..11
  const int by = pp & 3;               // n-tile 0..3
  const int bz = pp >> 2;              // 0=Q 1=K 2=V

  const unsigned short* Wp = Wall + (size_t)bz * HD * HD;
  const int m0 = bx * 256;
  const int n0 = by * 256;

  const int cl = lane & 15;
  const int qd = lane >> 4;
  const int lr = lane >> 3;                              // 0..7
  const int cgl = (((lane & 7) ^ (lane >> 3)) << 3);     // A gather swizzle

  f32x4 acc[4][4];
#pragma unroll
  for (int i = 0; i < 4; i++)
#pragma unroll
    for (int j = 0; j < 4; j++) acc[i][j] = (f32x4){0.f, 0.f, 0.f, 0.f};

  // --- stage one 16KB A-stripe (rows with bit5==mh) of k-offset k0 into
  // buf b. Wave w covers 8 rows: (w>>2)*64 + mh*32 + (w&3)*8 (+ lane>>3).
  // LDS slot s at row r holds global chunk s^(r&7).
  auto stageA = [&](int b, int mh, int k0) {
    int ar0 = ((w >> 2) << 6) + (mh << 5) + ((w & 3) << 3);
    gll16(X + (size_t)(m0 + ar0 + lr) * HD + k0 + cgl, &As[b][ar0 * 64]);
  };
  // --- stage one 16KB B-stripe (k-half kh) into buf b, layout
  // [kh][256 rows][4 slots], LINEAR (slot s = chunk s). Wave w covers rows
  // w*16 .. w*16+15; lane -> (row w*16 + (lane>>2), slot lane&3).
  auto stageB = [&](int b, int kh, int k0) {
    int rB = (w << 4) + (lane >> 2);
    gll16(Wp + (size_t)(n0 + rB) * HD + k0 + (kh << 5) + ((lane & 3) << 3),
          &Bs[b][(kh << 13) + (w << 9)]);
  };

#define PHASE(bi, ks, mh, STG)                                                 \
  {                                                                            \
    short8 af[2];                                                              \
    _Pragma("unroll") for (int i = 0; i < 2; i++) {                            \
      int r = wm * 64 + (mh) * 32 + i * 16 + cl;                               \
      af[i] = *(const short8*)(&As[bi][r * 64] +                               \
                               ((((ks) * 4 + qd) ^ (r & 7)) << 3));            \
    }                                                                          \
    short8 bf[4];                                                              \
    _Pragma("unroll") for (int j = 0; j < 4; j++) {                            \
      int r = wn * 64 + j * 16 + cl;                                           \
      bf[j] = *(const short8*)(&Bs[bi][((ks) << 13) + r * 32 + qd * 8]);       \
    }                                                                          \
    STG;                                                                       \
    __builtin_amdgcn_s_barrier();                                              \
    asm volatile("s_waitcnt lgkmcnt(0)");                                      \
    __builtin_amdgcn_sched_barrier(0);                                         \
    __builtin_amdgcn_s_setprio(1);                                             \
    if (bz < 2) {                                                              \
      _Pragma("unroll") for (int i = 0; i < 2; i++)                            \
        _Pragma("unroll") for (int j = 0; j < 4; j++)                          \
          acc[(mh) * 2 + i][j] = __builtin_amdgcn_mfma_f32_16x16x32_bf16(      \
              bf[j], af[i], acc[(mh) * 2 + i][j], 0, 0, 0);                    \
    } else {                                                                   \
      _Pragma("unroll") for (int i = 0; i < 2; i++)                            \
        _Pragma("unroll") for (int j = 0; j < 4; j++)                          \
          acc[(mh) * 2 + i][j] = __builtin_amdgcn_mfma_f32_16x16x32_bf16(      \
              af[i], bf[j], acc[(mh) * 2 + i][j], 0, 0, 0);                    \
    }                                                                          \
    __builtin_amdgcn_s_setprio(0);                                             \
  }

#define PH_END()                    \
  __builtin_amdgcn_s_barrier();     \
  __builtin_amdgcn_sched_barrier(0);

#define PH_VMC()                       \
  __builtin_amdgcn_sched_barrier(0);   \
  asm volatile("s_waitcnt vmcnt(2)");  \
  __builtin_amdgcn_sched_barrier(0);

  // ---- prologue: tile0 fully + tile1's B-ks0,A-mh0 (last 2 issued) ----
  stageA(0, 0, 0);
  stageA(0, 1, 0);
  stageB(0, 0, 0);
  stageB(0, 1, 0);
  stageB(1, 0, 64);
  stageA(1, 0, 64);
  asm volatile("s_waitcnt vmcnt(2)");
  __builtin_amdgcn_s_barrier();
  __builtin_amdgcn_sched_barrier(0);

#pragma unroll 1
  for (int it = 0; it < 8; it++) {
    const int t0k = it * 128;            // k of tile t0=2*it
    const int kB = t0k + 64;             // k of tile t1 (always valid)
    const int kA = (t0k + 128) & 1023;   // k of t0+2 (wraps to junk on tail)
    const int kC = (t0k + 192) & 1023;   // k of t1+2 (wraps to junk on tail)

    PHASE(0, 0, 0, stageA(1, 1, kB));   // ph1
    PH_END();
    PHASE(0, 0, 1, stageB(1, 1, kB));   // ph2
    PH_END();
    PHASE(0, 1, 0, stageB(0, 0, kA));   // ph3
    PH_END();
    PHASE(0, 1, 1, stageA(0, 0, kA));   // ph4
    PH_VMC();                           // buf1(t1) complete
    PH_END();
    PHASE(1, 0, 0, stageA(0, 1, kA));   // ph5
    PH_END();
    PHASE(1, 0, 1, stageB(0, 1, kA));   // ph6
    PH_END();
    PHASE(1, 1, 0, stageB(1, 0, kC));   // ph7
    PH_END();
    PHASE(1, 1, 1, stageA(1, 0, kC));   // ph8
    PH_VMC();                           // buf0(t0+2) complete
    PH_END();
  }

  // ---- epilogue (per-wave 64x64 at (m0+wm*64, n0+wn*64)) ----
  if (bz == 2) {
    // normal orientation: acc[mf][nf] = D[m(s)][n(feature)]
    const int hh = (n0 >> 6) + wn;
#pragma unroll
    for (int mf = 0; mf < 4; mf++) {
      int mb = m0 + wm * 64 + mf * 16 + qd * 4;
      int bb = mb >> 11, ssb = mb & (SEQ - 1);
      f32x4 mk = *(const f32x4*)(mask + bb * SEQ + ssb);
      f32x4 w4;
#pragma unroll
      for (int r = 0; r < 4; r++) w4[r] = __expf(mk[r]);
      int colp = (ssb & ~31) | ((ssb & 12) << 1) | (((ssb >> 4) & 1) << 2);
#pragma unroll
      for (int nf = 0; nf < 4; nf++) {
        int feat = n0 + wn * 64 + nf * 16 + cl;
        int dd = nf * 16 + cl;
        float bn = bv[feat];
        u32x2 pk;
        pk[0] = pk2h((acc[mf][nf][0] + bn) * w4[0], (acc[mf][nf][1] + bn) * w4[1]);
        pk[1] = pk2h((acc[mf][nf][2] + bn) * w4[2], (acc[mf][nf][3] + bn) * w4[3]);
        *(u32x2*)(Vt + ((size_t)((bb * NHEADS + hh) * DHEAD + dd)) * SEQ + colp) = pk;
      }
    }
  } else {
    // transposed: acc[mf][nf] = D[n(feature)][m(s)]
    const float* bias = (bz == 0) ? bq : bk;
    unsigned short* Out = (bz == 0) ? Qo : Ko;
    const float qs = (bz == 0) ? 0.125f * 1.4426950408889634f : 1.0f;
    const int hh = (n0 >> 6) + wn;
#pragma unroll
    for (int nf = 0; nf < 4; nf++) {
      int nb = n0 + wn * 64 + nf * 16 + qd * 4;
      f32x4 b4 = *(const f32x4*)(bias + nb);
      int ddb = nf * 16 + qd * 4;
#pragma unroll
      for (int mf = 0; mf < 4; mf++) {
        int s = m0 + wm * 64 + mf * 16 + cl;
        int bb = s >> 11, ss = s & (SEQ - 1);
        f32x4 rl = *(const f32x4*)(rel + ss * DHEAD + ddb);
        float x0 = acc[mf][nf][0] + b4[0];
        float x1 = acc[mf][nf][1] + b4[1];
        float x2 = acc[mf][nf][2] + b4[2];
        float x3 = acc[mf][nf][3] + b4[3];
        float y0 = (x0 * rl[1] - x1 * rl[0]) * qs;
        float y1 = (x1 * rl[1] + x0 * rl[0]) * qs;
        float y2 = (x2 * rl[3] - x3 * rl[2]) * qs;
        float y3 = (x3 * rl[3] + x2 * rl[2]) * qs;
        u32x2 pk;
        pk[0] = pk2h(y0, y1);
        pk[1] = pk2h(y2, y3);
        *(u32x2*)(Out + (((size_t)(bb * NHEADS + hh)) * SEQ + ss) * DHEAD + ddb) = pk;
      }
    }
  }
#undef PHASE
#undef PH_END
#undef PH_VMC
}

// ---------------- flash attention (unchanged) ----------------
// Q: [64][2048][64] bf16 pre-scaled by 0.125*log2e; K: [64][2048][64] bf16;
// Vt: [64][64][2048] bf16 (columns permuted, mask-scaled); wm: [4][2048] bf16.
// out: [4][2048][1024] f32.  Softmax inner op = one exp2 per score.
__global__ __launch_bounds__(256, 2) void attn(
    const unsigned short* __restrict__ Q,
    const unsigned short* __restrict__ K,
    const unsigned short* __restrict__ Vt,
    const unsigned short* __restrict__ wmask,
    float* __restrict__ out) {
  __shared__ __align__(16) unsigned short Ks[2][128 * 64];   // [key][d], swizzled
  __shared__ __align__(16) unsigned short Vs[2][64 * 128];   // [d][key'], swizzled

  const int t = threadIdx.x;
  const int lane = t & 63;
  const int w = t >> 6;

  // XCD swizzle: all 16 q-tiles of a bh on one XCD
  const int n = blockIdx.x;          // 0..1023
  const int xcd = n & 7;
  const int li = n >> 3;             // 0..127
  const int bh = xcd * 8 + (li >> 4);
  const int qt = li & 15;

  const int b = bh >> 4, h = bh & 15;
  const int s0 = qt * 128;
  const unsigned short* Qp = Q + (size_t)bh * SEQ * DHEAD;
  const unsigned short* Kp = K + (size_t)bh * SEQ * DHEAD;
  const unsigned short* Vp = Vt + (size_t)bh * DHEAD * SEQ;
  const unsigned short* wmp = wmask + b * SEQ;

  const int cl = lane & 15;
  const int qd = lane >> 4;

  short8 qf[2][2];
#pragma unroll
  for (int mt = 0; mt < 2; mt++)
#pragma unroll
    for (int ks = 0; ks < 2; ks++)
      qf[mt][ks] = *(const short8*)(Qp + (size_t)(s0 + w * 32 + mt * 16 + cl) * DHEAD +
                                    ks * 32 + qd * 8);

  f32x4 ov[2][4];   // [mt][dt], D[d][q]: q=cl, d rows = dt*16+qd*4+r
  f32x4 ovl[2];     // l accumulator (sum_k w_k p_k), all rows identical
#pragma unroll
  for (int mt = 0; mt < 2; mt++) {
    ovl[mt] = (f32x4){0.f, 0.f, 0.f, 0.f};
#pragma unroll
    for (int dt = 0; dt < 4; dt++) ov[mt][dt] = (f32x4){0.f, 0.f, 0.f, 0.f};
  }

  auto stage = [&](int bi, int kt) {
#pragma unroll
    for (int j = 0; j < 4; j++) {
      int r0 = w * 32 + j * 8;
      int r = r0 + (lane >> 3);
      int c = (lane & 7) ^ (r & 7);
      gll16(Kp + (size_t)(kt + r) * DHEAD + c * 8, &Ks[bi][r0 * 64]);
    }
#pragma unroll
    for (int j = 0; j < 4; j++) {
      int r0 = w * 16 + j * 4;
      int r = r0 + (lane >> 4);
      int c = (lane & 15) ^ (r & 7);
      gll16(Vp + (size_t)r * SEQ + kt + c * 8, &Vs[bi][r0 * 128]);
    }
  };

  stage(0, 0);

  for (int it = 0; it < SEQ / 128; it++) {
    const int kt = it * 128;
    const int bi = it & 1;
    __syncthreads();
    if (it + 1 < SEQ / 128) stage(1 - bi, kt + 128);
    const unsigned short* Ksb = &Ks[bi][0];
    const unsigned short* Vsb = &Vs[bi][0];

    // w A-fragment for l-MFMA: keys in P's permuted k-order
    short8 wf[4];
#pragma unroll
    for (int c = 0; c < 4; c++) {
      u32x2 w0 = *(const u32x2*)(wmp + kt + c * 32 + qd * 4);
      u32x2 w1 = *(const u32x2*)(wmp + kt + c * 32 + 16 + qd * 4);
      u32x4 ww = {w0[0], w0[1], w1[0], w1[1]};
      wf[c] = __builtin_bit_cast(short8, ww);
    }

    // ---- scores: D[m=key][n=q] ----
    f32x4 sc[2][8];
#pragma unroll
    for (int mt = 0; mt < 2; mt++)
#pragma unroll
      for (int nt = 0; nt < 8; nt++) sc[mt][nt] = (f32x4){0.f, 0.f, 0.f, 0.f};
#pragma unroll
    for (int ks = 0; ks < 2; ks++) {
#pragma unroll
      for (int nt = 0; nt < 8; nt++) {
        int krow = nt * 16 + cl;
        short8 kf = *(const short8*)(Ksb + krow * 64 +
                                     (((ks * 4 + qd) ^ (krow & 7)) << 3));
        sc[0][nt] = __builtin_amdgcn_mfma_f32_16x16x32_bf16(kf, qf[0][ks], sc[0][nt], 0, 0, 0);
        sc[1][nt] = __builtin_amdgcn_mfma_f32_16x16x32_bf16(kf, qf[1][ks], sc[1][nt], 0, 0, 0);
      }
    }

    // ---- softmax: p = exp2(s) ----
    unsigned pw[2][8][2];
#pragma unroll
    for (int mt = 0; mt < 2; mt++) {
#pragma unroll
      for (int nt = 0; nt < 8; nt++) {
        float p0 = __builtin_amdgcn_exp2f(sc[mt][nt][0]);
        float p1 = __builtin_amdgcn_exp2f(sc[mt][nt][1]);
        float p2 = __builtin_amdgcn_exp2f(sc[mt][nt][2]);
        float p3 = __builtin_amdgcn_exp2f(sc[mt][nt][3]);
        pw[mt][nt][0] = pk2h(p0, p1);
        pw[mt][nt][1] = pk2h(p2, p3);
      }
    }

    // ---- O += V' * P (permuted k-order; V columns pre-permuted to match) ----
#pragma unroll
    for (int c = 0; c < 4; c++) {
      u32x4 bb0 = {pw[0][2 * c][0], pw[0][2 * c][1], pw[0][2 * c + 1][0], pw[0][2 * c + 1][1]};
      u32x4 bb1 = {pw[1][2 * c][0], pw[1][2 * c][1], pw[1][2 * c + 1][0], pw[1][2 * c + 1][1]};
      short8 bf0 = __builtin_bit_cast(short8, bb0);
      short8 bf1 = __builtin_bit_cast(short8, bb1);
      ovl[0] = __builtin_amdgcn_mfma_f32_16x16x32_bf16(wf[c], bf0, ovl[0], 0, 0, 0);
      ovl[1] = __builtin_amdgcn_mfma_f32_16x16x32_bf16(wf[c], bf1, ovl[1], 0, 0, 0);
#pragma unroll
      for (int dt = 0; dt < 4; dt++) {
        int vrow = dt * 16 + cl;
        short8 vf = *(const short8*)(Vsb + vrow * 128 +
                                     (((c * 4 + qd) ^ (vrow & 7)) << 3));
        ov[0][dt] = __builtin_amdgcn_mfma_f32_16x16x32_bf16(vf, bf0, ov[0][dt], 0, 0, 0);
        ov[1][dt] = __builtin_amdgcn_mfma_f32_16x16x32_bf16(vf, bf1, ov[1][dt], 0, 0, 0);
      }
    }
  }

  // ---- epilogue: O[d][q] / l(q) ----
#pragma unroll
  for (int mt = 0; mt < 2; mt++) {
    float rl = 1.0f / ovl[mt][0];
    int s = s0 + w * 32 + mt * 16 + cl;
    float* ob = out + ((size_t)b * SEQ + s) * HD + h * DHEAD;
#pragma unroll
    for (int dt = 0; dt < 4; dt++) {
      f32x4 o;
      o[0] = ov[mt][dt][0] * rl;
      o[1] = ov[mt][dt][1] * rl;
      o[2] = ov[mt][dt][2] * rl;
      o[3] = ov[mt][dt][3] * rl;
      *(f32x4*)(ob + dt * 16 + qd * 4) = o;
    }
  }
}

extern "C" void kernel_launch(void* const* d_in, const int* in_sizes, int n_in,
                              void* d_out, int out_size, void* d_ws, size_t ws_size,
                              hipStream_t stream) {
  const float* hidden = (const float*)d_in[0];
  const float* mask   = (const float*)d_in[1];
  const float* rel    = (const float*)d_in[2];
  const float* Wq     = (const float*)d_in[3];
  const float* bq     = (const float*)d_in[4];
  const float* Wk     = (const float*)d_in[5];
  const float* bk     = (const float*)d_in[6];
  const float* Wv     = (const float*)d_in[7];
  const float* bv     = (const float*)d_in[8];
  float* out = (float*)d_out;

  unsigned short* Xb = (unsigned short*)d_ws;          // 8192*1024
  unsigned short* Wb = Xb + (size_t)MTOT * HD;         // 3*1024*1024
  unsigned short* Qb = Wb + (size_t)3 * HD * HD;       // 8192*1024
  unsigned short* Kb = Qb + (size_t)MTOT * HD;
  unsigned short* Vb = Kb + (size_t)MTOT * HD;
  unsigned short* Wm = Vb + (size_t)MTOT * HD;         // 4*2048

  {
    int n4 = MTOT * HD / 4;
    cvt_bf16<<<n4 / 256, 256, 0, stream>>>(hidden, Xb, n4);
  }
  prep<<<(3 * WQ4 + BATCH * SEQ / 4) / 256, 256, 0, stream>>>(Wq, Wk, Wv, mask, Wb, Wm);
  qkv_gemm<<<dim3(384), 1024, 0, stream>>>(Xb, Wb, bq, bk, bv, rel, mask, Qb, Kb, Vb);
  attn<<<dim3(1024), 256, 0, stream>>>(Qb, Kb, Vb, Wm, out);
}

// Round 6
// 275.970 us; speedup vs baseline: 1.3462x; 1.3462x over previous
//
#include <hip/hip_runtime.h>

typedef __attribute__((ext_vector_type(8))) short short8;
typedef __attribute__((ext_vector_type(4))) float f32x4;
typedef __attribute__((ext_vector_type(4))) unsigned int u32x4;
typedef __attribute__((ext_vector_type(2))) unsigned int u32x2;
typedef __attribute__((ext_vector_type(4))) unsigned short u16x4;

#define NHEADS 16
#define DHEAD 64
#define SEQ 2048
#define BATCH 4
#define HD 1024
#define MTOT 8192  // BATCH*SEQ

// RNE f32->bf16 (cold paths)
static __device__ __forceinline__ unsigned short f2b(float x) {
  unsigned u = __builtin_bit_cast(unsigned, x);
  u += 0x7fffu + ((u >> 16) & 1u);
  return (unsigned short)(u >> 16);
}

// round-half-up pack of two f32 -> bf16x2 (<=0.5 ulp, 4 insts; hot paths)
static __device__ __forceinline__ unsigned pk2h(float lo, float hi) {
  unsigned a = __builtin_bit_cast(unsigned, lo) + 0x8000u;
  unsigned b = __builtin_bit_cast(unsigned, hi) + 0x8000u;
  return (a >> 16) | (b & 0xffff0000u);
}

// async global -> LDS, 16B per lane. LDS dst = wave-uniform base + lane*16.
static __device__ __forceinline__ void gll16(const void* g, void* l) {
  __builtin_amdgcn_global_load_lds(
      (const __attribute__((address_space(1))) unsigned int*)g,
      (__attribute__((address_space(3))) unsigned int*)l, 16, 0, 0);
}

// ---------------- f32 -> bf16 conversion (hidden states) ----------------
__global__ void cvt_bf16(const float* __restrict__ src,
                         unsigned short* __restrict__ dst, int n4) {
  int i = blockIdx.x * blockDim.x + threadIdx.x;
  if (i < n4) {
    f32x4 v = ((const f32x4*)src)[i];
    u16x4 o;
    o[0] = f2b(v[0]); o[1] = f2b(v[1]); o[2] = f2b(v[2]); o[3] = f2b(v[3]);
    ((u16x4*)dst)[i] = o;
  }
}

// ---- combined prep: Wq/Wk/Wv -> bf16, wmask = bf16(exp(mask)) ----
#define WQ4 (HD * HD / 4)   // 262144 vec4s per weight matrix
__global__ void prep(const float* __restrict__ Wq, const float* __restrict__ Wk,
                     const float* __restrict__ Wv, const float* __restrict__ mask,
                     unsigned short* __restrict__ Wb,
                     unsigned short* __restrict__ Wm) {
  int i = blockIdx.x * blockDim.x + threadIdx.x;
  if (i < 3 * WQ4) {
    int rg = i / WQ4;
    int idx = i - rg * WQ4;
    const float* src = (rg == 0) ? Wq : (rg == 1) ? Wk : Wv;
    f32x4 v = ((const f32x4*)src)[idx];
    u16x4 o;
    o[0] = f2b(v[0]); o[1] = f2b(v[1]); o[2] = f2b(v[2]); o[3] = f2b(v[3]);
    ((u16x4*)(Wb + (size_t)rg * HD * HD))[idx] = o;
  } else {
    int j = i - 3 * WQ4;            // 0..2047 vec4s of mask
    f32x4 v = ((const f32x4*)mask)[j];
    u16x4 o;
    o[0] = f2b(__expf(v[0])); o[1] = f2b(__expf(v[1]));
    o[2] = f2b(__expf(v[2])); o[3] = f2b(__expf(v[3]));
    ((u16x4*)Wm)[j] = o;
  }
}

// ------- fused QKV GEMM: 128x128, 256 thr, counted-vmcnt pipeline -------
// R13: allocator findings R9-R12: 512/1024-thr blocks get VGPR pinned to
// 128/64 (spilling acc); 256-thr blocks allocate pressure-driven (R0/R8:
// 132; m97: 164) with no spill. So: 256 thr, per-wave state <=~120 VGPR by
// construction. 4 waves as 1M x 4N: per-wave 128 rows x 32 cols ->
// acc[8][2]=64 VGPR, bf[2][2] held=16, af[2] transient=8.
// LDS: dbuf x (A 128x64 + B 128x64) x 2B = 64KB -> 2 blocks/CU. All tiles
// in the XOR-swizzled [row][8 slot] layout (slot s at row r = global chunk
// s^(r&7)) -- 0 bank conflicts R0-R11. (R12's [kh][row][4-slot] B layout
// was an 8-way conflict + 64B-segment fetch amplification: reverted.)
//
// Pipeline (per K-tile iter, 2 sync points, vmcnt NEVER 0):
//  A staged as 4 row-quarter units (Aq = rows q*32..q*32+31, 4KB each);
//  B as 4 units (rows q*32..). Compute region R1 reads A rows 0..63 (mq
//  0,1) + all B; R2 reads A rows 64..127 (bf held). Reads come from buf
//  bi, stages go to buf bi^1 -- never the same buffer, so only the sync
//  points order cross-wave LDS visibility.
//  Iter t (reads tile t from buf bi, stages tile t+1 into bi^1):
//   S1: vmcnt(2)+barrier  [drains prev iter's first-6 issues = A0,A1,B0,
//        B1,B2,B3 of tile t; leaves A2,A3 in flight]
//   R1: issue A0,A1,B0,B1 (t+1); load bf[2][2]; MFMA mq=0,1 (16)
//   S2: vmcnt(4)+barrier  [drains prev A2,A3; leaves this R1's 4]
//   R2: issue B2,B3,A2,A3 (t+1); MFMA mq=2,3 (16)
//  Cover: worst-case unit (B2/B3: issued R2, read next S1) ~half iter
//  (~600cy) > L2 latency ~200-300cy; others ~1 full iter.
// Prologue: stage tile0's 8 units in the same order. Tail wraps k by
// &1023 (junk staged, never computed, in-bounds).
// R8 kept: m-slab XCD swizzle (FETCH 211->61MB), pre-swizzled-global
// gather so gll16's linear LDS write lands the XOR layout.
__global__ __launch_bounds__(256) void qkv_gemm(
    const unsigned short* __restrict__ X,
    const unsigned short* __restrict__ Wall,
    const float* __restrict__ bq, const float* __restrict__ bk,
    const float* __restrict__ bv,
    const float* __restrict__ rel,          // [2048][64] f32
    const float* __restrict__ mask,         // [4][2048] f32
    unsigned short* __restrict__ Qo,
    unsigned short* __restrict__ Ko,
    unsigned short* __restrict__ Vt) {
  __shared__ __align__(16) unsigned short As[2][128 * 64];
  __shared__ __align__(16) unsigned short Bs[2][128 * 64];

  const int t = threadIdx.x;           // 0..255
  const int lane = t & 63;
  const int w = t >> 6;                // 0..3 == wn (N strip)

  // XCD swizzle: 8 m-tiles pinned per XCD (2MB X slab, L2-resident);
  // consecutive li share a panel so each W panel is fetched ~once per XCD.
  const int n = blockIdx.x;            // 0..1535
  const int xcd = n & 7;
  const int li = n >> 3;               // 0..191
  const int bx = xcd * 8 + (li & 7);   // m-tile 0..63
  const int pp = li >> 3;              // 0..23
  const int by = pp & 7;               // n-tile 0..7
  const int bz = pp >> 3;              // 0=Q 1=K 2=V

  const unsigned short* Wp = Wall + (size_t)bz * HD * HD;
  const int m0 = bx * 128;
  const int n0 = by * 128;

  const int cl = lane & 15;
  const int qd = lane >> 4;

  f32x4 acc[8][2];
#pragma unroll
  for (int i = 0; i < 8; i++)
#pragma unroll
    for (int j = 0; j < 2; j++) acc[i][j] = (f32x4){0.f, 0.f, 0.f, 0.f};

  // stage one 4KB unit = rows q*32..q*32+31, 64 k. Thread t -> row
  // q*32 + (t>>3), global chunk (t&7)^(row&7); LDS write is linear so
  // slot (t&7) at that row holds chunk (t&7)^(row&7) == XOR layout.
  auto stageA = [&](int b, int q, int k0) {
    int rr = (q << 5) + (t >> 3);
    gll16(X + (size_t)(m0 + rr) * HD + k0 + (((t & 7) ^ (rr & 7)) << 3),
          &As[b][((q << 5) + (w << 3)) * 64]);
  };
  auto stageB = [&](int b, int q, int k0) {
    int rr = (q << 5) + (t >> 3);
    gll16(Wp + (size_t)(n0 + rr) * HD + k0 + (((t & 7) ^ (rr & 7)) << 3),
          &Bs[b][((q << 5) + (w << 3)) * 64]);
  };

#define SYNC(N)                               \
  __builtin_amdgcn_sched_barrier(0);          \
  asm volatile("s_waitcnt vmcnt(" #N ")");    \
  __builtin_amdgcn_sched_barrier(0);          \
  __builtin_amdgcn_s_barrier();               \
  __builtin_amdgcn_sched_barrier(0);

  // ---- prologue: tile0, order A0,A1,B0,B1,B2,B3,A2,A3 ----
  stageA(0, 0, 0); stageA(0, 1, 0);
  stageB(0, 0, 0); stageB(0, 1, 0);
  stageB(0, 2, 0); stageB(0, 3, 0);
  stageA(0, 2, 0); stageA(0, 3, 0);

#pragma unroll 1
  for (int it = 0; it < 16; it++) {
    const int bi = it & 1;
    const int nb = bi ^ 1;
    const int kn = ((it + 1) * 64) & 1023;   // tail wraps to junk
    const unsigned short* Asb = &As[bi][0];
    const unsigned short* Bsb = &Bs[bi][0];

    SYNC(2);   // A0,A1,B0..B3 of tile it landed (A2,A3 may fly)

    // R1 issues (tile it+1)
    stageA(nb, 0, kn); stageA(nb, 1, kn);
    stageB(nb, 0, kn); stageB(nb, 1, kn);

    // bf for this wave's 32 B-rows, both K-halves (held through iter)
    short8 bf[2][2];
#pragma unroll
    for (int j = 0; j < 2; j++) {
      int r = w * 32 + j * 16 + cl;
      const unsigned short* rp = &Bsb[r * 64];
#pragma unroll
      for (int ks = 0; ks < 2; ks++)
        bf[j][ks] = *(const short8*)(rp + (((ks * 4 + qd) ^ (r & 7)) << 3));
    }

    __builtin_amdgcn_s_setprio(1);
#pragma unroll
    for (int mq = 0; mq < 2; mq++) {
#pragma unroll
      for (int ks = 0; ks < 2; ks++) {
        short8 af[2];
#pragma unroll
        for (int i = 0; i < 2; i++) {
          int r = mq * 32 + i * 16 + cl;
          af[i] = *(const short8*)(&Asb[r * 64] +
                                   (((ks * 4 + qd) ^ (r & 7)) << 3));
        }
        if (bz < 2) {
#pragma unroll
          for (int i = 0; i < 2; i++)
#pragma unroll
            for (int j = 0; j < 2; j++)
              acc[mq * 2 + i][j] = __builtin_amdgcn_mfma_f32_16x16x32_bf16(
                  bf[j][ks], af[i], acc[mq * 2 + i][j], 0, 0, 0);
        } else {
#pragma unroll
          for (int i = 0; i < 2; i++)
#pragma unroll
            for (int j = 0; j < 2; j++)
              acc[mq * 2 + i][j] = __builtin_amdgcn_mfma_f32_16x16x32_bf16(
                  af[i], bf[j][ks], acc[mq * 2 + i][j], 0, 0, 0);
        }
      }
    }
    __builtin_amdgcn_s_setprio(0);

    SYNC(4);   // prev A2,A3 landed (this iter's R1 4 units may fly)

    // R2 issues (tile it+1) -- B first so newest-2 at next S1 are A2,A3
    stageB(nb, 2, kn); stageB(nb, 3, kn);
    stageA(nb, 2, kn); stageA(nb, 3, kn);

    __builtin_amdgcn_s_setprio(1);
#pragma unroll
    for (int mq = 2; mq < 4; mq++) {
#pragma unroll
      for (int ks = 0; ks < 2; ks++) {
        short8 af[2];
#pragma unroll
        for (int i = 0; i < 2; i++) {
          int r = mq * 32 + i * 16 + cl;
          af[i] = *(const short8*)(&Asb[r * 64] +
                                   (((ks * 4 + qd) ^ (r & 7)) << 3));
        }
        if (bz < 2) {
#pragma unroll
          for (int i = 0; i < 2; i++)
#pragma unroll
            for (int j = 0; j < 2; j++)
              acc[mq * 2 + i][j] = __builtin_amdgcn_mfma_f32_16x16x32_bf16(
                  bf[j][ks], af[i], acc[mq * 2 + i][j], 0, 0, 0);
        } else {
#pragma unroll
          for (int i = 0; i < 2; i++)
#pragma unroll
            for (int j = 0; j < 2; j++)
              acc[mq * 2 + i][j] = __builtin_amdgcn_mfma_f32_16x16x32_bf16(
                  af[i], bf[j][ks], acc[mq * 2 + i][j], 0, 0, 0);
        }
      }
    }
    __builtin_amdgcn_s_setprio(0);
  }
#undef SYNC

  // ---- epilogue (per-wave 128 rows x 32 cols at (m0, n0 + w*32)) ----
  if (bz == 2) {
    // normal orientation: acc[mf][nf] = D[m(s)][n(feature)]
#pragma unroll
    for (int mf = 0; mf < 8; mf++) {
      int mb = m0 + mf * 16 + qd * 4;
      int bb = mb >> 11, ssb = mb & (SEQ - 1);
      f32x4 mk = *(const f32x4*)(mask + bb * SEQ + ssb);
      f32x4 w4;
#pragma unroll
      for (int r = 0; r < 4; r++) w4[r] = __expf(mk[r]);
      int colp = (ssb & ~31) | ((ssb & 12) << 1) | (((ssb >> 4) & 1) << 2);
#pragma unroll
      for (int nf = 0; nf < 2; nf++) {
        int feat = n0 + w * 32 + nf * 16 + cl;
        int hh = feat >> 6;
        int dd = feat & 63;
        float bn = bv[feat];
        u32x2 pk;
        pk[0] = pk2h((acc[mf][nf][0] + bn) * w4[0], (acc[mf][nf][1] + bn) * w4[1]);
        pk[1] = pk2h((acc[mf][nf][2] + bn) * w4[2], (acc[mf][nf][3] + bn) * w4[3]);
        *(u32x2*)(Vt + ((size_t)((bb * NHEADS + hh) * DHEAD + dd)) * SEQ + colp) = pk;
      }
    }
  } else {
    // transposed: acc[mf][nf] = D[n(feature)][m(s)]
    const float* bias = (bz == 0) ? bq : bk;
    unsigned short* Out = (bz == 0) ? Qo : Ko;
    const float qs = (bz == 0) ? 0.125f * 1.4426950408889634f : 1.0f;
#pragma unroll
    for (int nf = 0; nf < 2; nf++) {
      int feat0 = n0 + w * 32 + nf * 16 + qd * 4;
      int hh = feat0 >> 6;
      int ddb = feat0 & 63;
      f32x4 b4 = *(const f32x4*)(bias + feat0);
#pragma unroll
      for (int mf = 0; mf < 8; mf++) {
        int s = m0 + mf * 16 + cl;
        int bb = s >> 11, ss = s & (SEQ - 1);
        f32x4 rl = *(const f32x4*)(rel + ss * DHEAD + ddb);
        float x0 = acc[mf][nf][0] + b4[0];
        float x1 = acc[mf][nf][1] + b4[1];
        float x2 = acc[mf][nf][2] + b4[2];
        float x3 = acc[mf][nf][3] + b4[3];
        float y0 = (x0 * rl[1] - x1 * rl[0]) * qs;
        float y1 = (x1 * rl[1] + x0 * rl[0]) * qs;
        float y2 = (x2 * rl[3] - x3 * rl[2]) * qs;
        float y3 = (x3 * rl[3] + x2 * rl[2]) * qs;
        u32x2 pk;
        pk[0] = pk2h(y0, y1);
        pk[1] = pk2h(y2, y3);
        *(u32x2*)(Out + (((size_t)(bb * NHEADS + hh)) * SEQ + ss) * DHEAD + ddb) = pk;
      }
    }
  }
}

// ---------------- flash attention (unchanged) ----------------
// Q: [64][2048][64] bf16 pre-scaled by 0.125*log2e; K: [64][2048][64] bf16;
// Vt: [64][64][2048] bf16 (columns permuted, mask-scaled); wm: [4][2048] bf16.
// out: [4][2048][1024] f32.  Softmax inner op = one exp2 per score.
__global__ __launch_bounds__(256, 2) void attn(
    const unsigned short* __restrict__ Q,
    const unsigned short* __restrict__ K,
    const unsigned short* __restrict__ Vt,
    const unsigned short* __restrict__ wmask,
    float* __restrict__ out) {
  __shared__ __align__(16) unsigned short Ks[2][128 * 64];   // [key][d], swizzled
  __shared__ __align__(16) unsigned short Vs[2][64 * 128];   // [d][key'], swizzled

  const int t = threadIdx.x;
  const int lane = t & 63;
  const int w = t >> 6;

  // XCD swizzle: all 16 q-tiles of a bh on one XCD
  const int n = blockIdx.x;          // 0..1023
  const int xcd = n & 7;
  const int li = n >> 3;             // 0..127
  const int bh = xcd * 8 + (li >> 4);
  const int qt = li & 15;

  const int b = bh >> 4, h = bh & 15;
  const int s0 = qt * 128;
  const unsigned short* Qp = Q + (size_t)bh * SEQ * DHEAD;
  const unsigned short* Kp = K + (size_t)bh * SEQ * DHEAD;
  const unsigned short* Vp = Vt + (size_t)bh * DHEAD * SEQ;
  const unsigned short* wmp = wmask + b * SEQ;

  const int cl = lane & 15;
  const int qd = lane >> 4;

  short8 qf[2][2];
#pragma unroll
  for (int mt = 0; mt < 2; mt++)
#pragma unroll
    for (int ks = 0; ks < 2; ks++)
      qf[mt][ks] = *(const short8*)(Qp + (size_t)(s0 + w * 32 + mt * 16 + cl) * DHEAD +
                                    ks * 32 + qd * 8);

  f32x4 ov[2][4];   // [mt][dt], D[d][q]: q=cl, d rows = dt*16+qd*4+r
  f32x4 ovl[2];     // l accumulator (sum_k w_k p_k), all rows identical
#pragma unroll
  for (int mt = 0; mt < 2; mt++) {
    ovl[mt] = (f32x4){0.f, 0.f, 0.f, 0.f};
#pragma unroll
    for (int dt = 0; dt < 4; dt++) ov[mt][dt] = (f32x4){0.f, 0.f, 0.f, 0.f};
  }

  auto stage = [&](int bi, int kt) {
#pragma unroll
    for (int j = 0; j < 4; j++) {
      int r0 = w * 32 + j * 8;
      int r = r0 + (lane >> 3);
      int c = (lane & 7) ^ (r & 7);
      gll16(Kp + (size_t)(kt + r) * DHEAD + c * 8, &Ks[bi][r0 * 64]);
    }
#pragma unroll
    for (int j = 0; j < 4; j++) {
      int r0 = w * 16 + j * 4;
      int r = r0 + (lane >> 4);
      int c = (lane & 15) ^ (r & 7);
      gll16(Vp + (size_t)r * SEQ + kt + c * 8, &Vs[bi][r0 * 128]);
    }
  };

  stage(0, 0);

  for (int it = 0; it < SEQ / 128; it++) {
    const int kt = it * 128;
    const int bi = it & 1;
    __syncthreads();
    if (it + 1 < SEQ / 128) stage(1 - bi, kt + 128);
    const unsigned short* Ksb = &Ks[bi][0];
    const unsigned short* Vsb = &Vs[bi][0];

    // w A-fragment for l-MFMA: keys in P's permuted k-order
    short8 wf[4];
#pragma unroll
    for (int c = 0; c < 4; c++) {
      u32x2 w0 = *(const u32x2*)(wmp + kt + c * 32 + qd * 4);
      u32x2 w1 = *(const u32x2*)(wmp + kt + c * 32 + 16 + qd * 4);
      u32x4 ww = {w0[0], w0[1], w1[0], w1[1]};
      wf[c] = __builtin_bit_cast(short8, ww);
    }

    // ---- scores: D[m=key][n=q] ----
    f32x4 sc[2][8];
#pragma unroll
    for (int mt = 0; mt < 2; mt++)
#pragma unroll
      for (int nt = 0; nt < 8; nt++) sc[mt][nt] = (f32x4){0.f, 0.f, 0.f, 0.f};
#pragma unroll
    for (int ks = 0; ks < 2; ks++) {
#pragma unroll
      for (int nt = 0; nt < 8; nt++) {
        int krow = nt * 16 + cl;
        short8 kf = *(const short8*)(Ksb + krow * 64 +
                                     (((ks * 4 + qd) ^ (krow & 7)) << 3));
        sc[0][nt] = __builtin_amdgcn_mfma_f32_16x16x32_bf16(kf, qf[0][ks], sc[0][nt], 0, 0, 0);
        sc[1][nt] = __builtin_amdgcn_mfma_f32_16x16x32_bf16(kf, qf[1][ks], sc[1][nt], 0, 0, 0);
      }
    }

    // ---- softmax: p = exp2(s) ----
    unsigned pw[2][8][2];
#pragma unroll
    for (int mt = 0; mt < 2; mt++) {
#pragma unroll
      for (int nt = 0; nt < 8; nt++) {
        float p0 = __builtin_amdgcn_exp2f(sc[mt][nt][0]);
        float p1 = __builtin_amdgcn_exp2f(sc[mt][nt][1]);
        float p2 = __builtin_amdgcn_exp2f(sc[mt][nt][2]);
        float p3 = __builtin_amdgcn_exp2f(sc[mt][nt][3]);
        pw[mt][nt][0] = pk2h(p0, p1);
        pw[mt][nt][1] = pk2h(p2, p3);
      }
    }

    // ---- O += V' * P (permuted k-order; V columns pre-permuted to match) ----
#pragma unroll
    for (int c = 0; c < 4; c++) {
      u32x4 bb0 = {pw[0][2 * c][0], pw[0][2 * c][1], pw[0][2 * c + 1][0], pw[0][2 * c + 1][1]};
      u32x4 bb1 = {pw[1][2 * c][0], pw[1][2 * c][1], pw[1][2 * c + 1][0], pw[1][2 * c + 1][1]};
      short8 bf0 = __builtin_bit_cast(short8, bb0);
      short8 bf1 = __builtin_bit_cast(short8, bb1);
      ovl[0] = __builtin_amdgcn_mfma_f32_16x16x32_bf16(wf[c], bf0, ovl[0], 0, 0, 0);
      ovl[1] = __builtin_amdgcn_mfma_f32_16x16x32_bf16(wf[c], bf1, ovl[1], 0, 0, 0);
#pragma unroll
      for (int dt = 0; dt < 4; dt++) {
        int vrow = dt * 16 + cl;
        short8 vf = *(const short8*)(Vsb + vrow * 128 +
                                     (((c * 4 + qd) ^ (vrow & 7)) << 3));
        ov[0][dt] = __builtin_amdgcn_mfma_f32_16x16x32_bf16(vf, bf0, ov[0][dt], 0, 0, 0);
        ov[1][dt] = __builtin_amdgcn_mfma_f32_16x16x32_bf16(vf, bf1, ov[1][dt], 0, 0, 0);
      }
    }
  }

  // ---- epilogue: O[d][q] / l(q) ----
#pragma unroll
  for (int mt = 0; mt < 2; mt++) {
    float rl = 1.0f / ovl[mt][0];
    int s = s0 + w * 32 + mt * 16 + cl;
    float* ob = out + ((size_t)b * SEQ + s) * HD + h * DHEAD;
#pragma unroll
    for (int dt = 0; dt < 4; dt++) {
      f32x4 o;
      o[0] = ov[mt][dt][0] * rl;
      o[1] = ov[mt][dt][1] * rl;
      o[2] = ov[mt][dt][2] * rl;
      o[3] = ov[mt][dt][3] * rl;
      *(f32x4*)(ob + dt * 16 + qd * 4) = o;
    }
  }
}

extern "C" void kernel_launch(void* const* d_in, const int* in_sizes, int n_in,
                              void* d_out, int out_size, void* d_ws, size_t ws_size,
                              hipStream_t stream) {
  const float* hidden = (const float*)d_in[0];
  const float* mask   = (const float*)d_in[1];
  const float* rel    = (const float*)d_in[2];
  const float* Wq     = (const float*)d_in[3];
  const float* bq     = (const float*)d_in[4];
  const float* Wk     = (const float*)d_in[5];
  const float* bk     = (const float*)d_in[6];
  const float* Wv     = (const float*)d_in[7];
  const float* bv     = (const float*)d_in[8];
  float* out = (float*)d_out;

  unsigned short* Xb = (unsigned short*)d_ws;          // 8192*1024
  unsigned short* Wb = Xb + (size_t)MTOT * HD;         // 3*1024*1024
  unsigned short* Qb = Wb + (size_t)3 * HD * HD;       // 8192*1024
  unsigned short* Kb = Qb + (size_t)MTOT * HD;
  unsigned short* Vb = Kb + (size_t)MTOT * HD;
  unsigned short* Wm = Vb + (size_t)MTOT * HD;         // 4*2048

  {
    int n4 = MTOT * HD / 4;
    cvt_bf16<<<n4 / 256, 256, 0, stream>>>(hidden, Xb, n4);
  }
  prep<<<(3 * WQ4 + BATCH * SEQ / 4) / 256, 256, 0, stream>>>(Wq, Wk, Wv, mask, Wb, Wm);
  qkv_gemm<<<dim3(1536), 256, 0, stream>>>(Xb, Wb, bq, bk, bv, rel, mask, Qb, Kb, Vb);
  attn<<<dim3(1024), 256, 0, stream>>>(Qb, Kb, Vb, Wm, out);
}